// Round 12
// baseline (220.365 us; speedup 1.0000x reference)
//
#include <hip/hip_runtime.h>

typedef unsigned short U16;
typedef __bf16 bf16x8 __attribute__((ext_vector_type(8)));
typedef float f32x4 __attribute__((ext_vector_type(4)));

__device__ inline float b2f(U16 u) {
    union { unsigned int i; float f; } v;
    v.i = ((unsigned int)u) << 16;
    return v.f;
}
__device__ inline U16 f2b(float f) {
    union { float f; unsigned int u; } v;
    v.f = f;
    unsigned int r = (v.u + 0x7fffu + ((v.u >> 16) & 1u)) >> 16;
    return (U16)r;
}

// async global->LDS, 16B per lane (LDS dest = wave-uniform base + lane*16)
__device__ inline void gld16(const void* g, void* l) {
    __builtin_amdgcn_global_load_lds(
        (const __attribute__((address_space(1))) void*)g,
        (__attribute__((address_space(3))) void*)l, 16, 0, 0);
}

// ------- Transpose + fp32->bf16: out[c][r] = bf16(in[r][c]), R x C /32 ------
__global__ void transpose_f2b(const float* __restrict__ in, U16* __restrict__ out,
                              int R, int C) {
    __shared__ float tile[32][33];
    int c0 = blockIdx.x * 32, r0 = blockIdx.y * 32;
    int tx = threadIdx.x, ty = threadIdx.y; // 32 x 8
#pragma unroll
    for (int i = 0; i < 32; i += 8)
        tile[ty + i][tx] = in[(size_t)(r0 + ty + i) * C + c0 + tx];
    __syncthreads();
#pragma unroll
    for (int i = 0; i < 32; i += 8)
        out[(size_t)(c0 + ty + i) * R + r0 + tx] = f2b(tile[tx][ty + i]);
}

// ------- LayerNorm: fp32 in -> bf16 out, one block (256 thr) per 1024-row ---
__global__ __launch_bounds__(256) void ln_kernel(const float* __restrict__ x,
                                                 const float* __restrict__ gamma,
                                                 const float* __restrict__ beta,
                                                 U16* __restrict__ xn) {
    int row = blockIdx.x;
    int t = threadIdx.x;
    float4 raw = ((const float4*)(x + (size_t)row * 1024))[t];
    float v[4] = { raw.x, raw.y, raw.z, raw.w };
    float s = v[0] + v[1] + v[2] + v[3];
    float s2 = v[0] * v[0] + v[1] * v[1] + v[2] * v[2] + v[3] * v[3];
#pragma unroll
    for (int off = 32; off >= 1; off >>= 1) {
        s  += __shfl_xor(s,  off);
        s2 += __shfl_xor(s2, off);
    }
    __shared__ float red[8];
    if ((t & 63) == 0) { red[(t >> 6) * 2] = s; red[(t >> 6) * 2 + 1] = s2; }
    __syncthreads();
    float S  = red[0] + red[2] + red[4] + red[6];
    float S2 = red[1] + red[3] + red[5] + red[7];
    float mu = S * (1.0f / 1024.0f);
    float var = S2 * (1.0f / 1024.0f) - mu * mu;
    float rstd = rsqrtf(var + 1e-5f);
    float4 g4 = ((const float4*)gamma)[t];
    float4 b4 = ((const float4*)beta)[t];
    ushort4 o;
    o.x = f2b((v[0] - mu) * rstd * g4.x + b4.x);
    o.y = f2b((v[1] - mu) * rstd * g4.y + b4.y);
    o.z = f2b((v[2] - mu) * rstd * g4.z + b4.z);
    o.w = f2b((v[3] - mu) * rstd * g4.w + b4.w);
    ((ushort4*)(xn + (size_t)row * 1024))[t] = o;
}

// ------ GEMM: C[M,N] = A[M,K] * Bt[N,K]^T (+fp32 bias), OutT = U16 or float -
// r12: async double-buffered K-loop (r10 attn recipe): prefetch tile k+1 via
// global_load_lds right after the barrier, compute tile k, ONE barrier/iter.
// The barrier's vmcnt drain waits on loads a full compute-tile old.
template <typename OutT>
__global__ __launch_bounds__(256) void gemm_bt(const U16* __restrict__ A,
                                               const U16* __restrict__ Bt,
                                               const float* __restrict__ bias,
                                               OutT* __restrict__ C,
                                               U16* __restrict__ vT,
                                               int M, int N, int K) {
    __shared__ __align__(16) U16 As[2][128 * 32];
    __shared__ __align__(16) U16 Bs[2][128 * 32];
    const int m0 = blockIdx.y * 128, n0 = blockIdx.x * 128;
    const int t = threadIdx.x;
    const int wave = t >> 6, lane = t & 63, l15 = lane & 15, quad = lane >> 4;
    const int wm = (wave >> 1) * 64, wn = (wave & 1) * 64;

    f32x4 acc[4][4];
#pragma unroll
    for (int i = 0; i < 4; i++)
#pragma unroll
        for (int j = 0; j < 4; j++)
            acc[i][j] = (f32x4){0.f, 0.f, 0.f, 0.f};

    const int c0i = t, c1i = 256 + t;
    const int r0 = c0i >> 2, kq0 = c0i & 3;
    const int r1 = c1i >> 2, kq1 = c1i & 3;

    // prefetch k-tile 0 into buf 0
    gld16(&A[(size_t)(m0 + r0) * K + kq0 * 8], &As[0][c0i * 8]);
    gld16(&Bt[(size_t)(n0 + r0) * K + kq0 * 8], &Bs[0][c0i * 8]);
    gld16(&A[(size_t)(m0 + r1) * K + kq1 * 8], &As[0][c1i * 8]);
    gld16(&Bt[(size_t)(n0 + r1) * K + kq1 * 8], &Bs[0][c1i * 8]);
    __syncthreads();

    const int KT = K >> 5;
    for (int kk = 0; kk < KT; kk++) {
        {   // async prefetch of tile kk+1 (wraps harmlessly on last iter)
            int nk = kk + 1 < KT ? (kk + 1) * 32 : 0;
            int nb = (kk + 1) & 1;
            gld16(&A[(size_t)(m0 + r0) * K + nk + kq0 * 8], &As[nb][c0i * 8]);
            gld16(&Bt[(size_t)(n0 + r0) * K + nk + kq0 * 8], &Bs[nb][c0i * 8]);
            gld16(&A[(size_t)(m0 + r1) * K + nk + kq1 * 8], &As[nb][c1i * 8]);
            gld16(&Bt[(size_t)(n0 + r1) * K + nk + kq1 * 8], &Bs[nb][c1i * 8]);
        }
        const U16* Ac = &As[kk & 1][0];
        const U16* Bc = &Bs[kk & 1][0];
        bf16x8 af[4], bfr[4];
#pragma unroll
        for (int i = 0; i < 4; i++)
            af[i] = *(const bf16x8*)&Ac[(wm + i * 16 + l15) * 32 + quad * 8];
#pragma unroll
        for (int j = 0; j < 4; j++)
            bfr[j] = *(const bf16x8*)&Bc[(wn + j * 16 + l15) * 32 + quad * 8];
#pragma unroll
        for (int i = 0; i < 4; i++)
#pragma unroll
            for (int j = 0; j < 4; j++)
                acc[i][j] = __builtin_amdgcn_mfma_f32_16x16x32_bf16(
                    af[i], bfr[j], acc[i][j], 0, 0, 0);
        __syncthreads();  // protects buf reuse AND makes prefetch visible
    }
    if (vT && n0 >= 2048) {
#pragma unroll
        for (int i = 0; i < 4; i++) {
#pragma unroll
            for (int j = 0; j < 4; j++) {
                int col = n0 + wn + j * 16 + l15 - 2048;
                int hh = col >> 6, dd = col & 63;
                int row0 = m0 + wm + i * 16 + quad * 4;
                int bb = row0 >> 11, nn = row0 & 2047;
                ushort4 st;
                st.x = f2b(acc[i][j][0]); st.y = f2b(acc[i][j][1]);
                st.z = f2b(acc[i][j][2]); st.w = f2b(acc[i][j][3]);
                *(ushort4*)&vT[((((size_t)bb * 16) + hh) * 64 + dd) * 2048 + nn] = st;
            }
        }
        return;
    }
#pragma unroll
    for (int i = 0; i < 4; i++) {
#pragma unroll
        for (int j = 0; j < 4; j++) {
            int col = n0 + wn + j * 16 + l15;
            float bv = bias ? bias[col] : 0.0f;
#pragma unroll
            for (int r = 0; r < 4; r++) {
                int row = m0 + wm + i * 16 + quad * 4 + r;
                float val = acc[i][j][r] + bv;
                if constexpr (sizeof(OutT) == 4)
                    C[(size_t)row * N + col] = val;
                else
                    C[(size_t)row * N + col] = f2b(val);
            }
        }
    }
}

// ---- MFMA flash attention: Bq=64, Bc=64, static softmax, async dbuf,
// XOR-swizzled LDS (K, V, AND P). r12: Bq back to 64 -> grid 1024 and LDS
// exactly 40960 B -> 4 blocks/CU (16 waves/CU, 2x the grid-capped r11).
// Swizzle: 16B chunk (row r, oct-slot j) holds global oct j^(r&7); reader
// slot for oct o of row r = o^(r&7). P stores scalar key k of row q at
// oct (k>>3)^(q&7), elem k&7 -> same read formula. Bit-identical values.
__global__ __launch_bounds__(256) void attn_kernel(const U16* __restrict__ qkv,
                                                   const U16* __restrict__ vT,
                                                   U16* __restrict__ attn_out) {
    const int qt = blockIdx.x;
    const int bh = blockIdx.y;
    const int b = bh >> 4, h = bh & 15;
    const int t = threadIdx.x;
    const int wave = t >> 6, lane = t & 63, l15 = lane & 15, quad = lane >> 4;
    const float sc2 = 0.125f * 1.44269504089f;  // scale * log2(e)

    __shared__ __align__(16) U16 Kt[2][64 * 64];   // 16384 B
    __shared__ __align__(16) U16 Vt[2][64 * 64];   // 16384 B
    __shared__ __align__(16) U16 Pb[4][16 * 64];   //  8192 B  -> total 40960

    const size_t base = (size_t)(b * 2048) * 3072;
    const U16* vTbh = vT + ((size_t)(b * 16 + h) * 64) * 2048;

    bf16x8 qf[2];
    {
        int qrow = qt * 64 + wave * 16 + l15;
        const U16* qp = qkv + base + (size_t)qrow * 3072 + h * 64;
        qf[0] = *(const bf16x8*)&qp[quad * 8];
        qf[1] = *(const bf16x8*)&qp[32 + quad * 8];
    }

    float l_i[4];
    f32x4 o[4];
#pragma unroll
    for (int r = 0; r < 4; r++) l_i[r] = 0.0f;
#pragma unroll
    for (int f = 0; f < 4; f++) o[f] = (f32x4){0.f, 0.f, 0.f, 0.f};

    // staging: chunk c -> LDS offset c*16B; row=c>>3, slot=c&7, oct=slot^(row&7)
    const int c0 = t, c1 = 256 + t;
    const int row0 = c0 >> 3, oct0 = (c0 & 7) ^ (row0 & 7);
    const int row1 = c1 >> 3, oct1 = (c1 & 7) ^ (row1 & 7);
    const int s0 = (quad ^ (l15 & 7)) * 8;   // reader slot offset; pair at s0^32

    // prefetch tile 0 into buf 0
    gld16(&qkv[base + (size_t)row0 * 3072 + 1024 + h * 64 + oct0 * 8], &Kt[0][c0 * 8]);
    gld16(&qkv[base + (size_t)row1 * 3072 + 1024 + h * 64 + oct1 * 8], &Kt[0][c1 * 8]);
    gld16(&vTbh[(size_t)row0 * 2048 + oct0 * 8], &Vt[0][c0 * 8]);
    gld16(&vTbh[(size_t)row1 * 2048 + oct1 * 8], &Vt[0][c1 * 8]);
    __syncthreads();

    for (int kt = 0; kt < 32; kt++) {
        {   // async prefetch of tile kt+1 (wraps harmlessly at the end)
            int nt = (kt + 1) & 31, nb = (kt + 1) & 1;
            gld16(&qkv[base + (size_t)(nt * 64 + row0) * 3072 + 1024 + h * 64 + oct0 * 8], &Kt[nb][c0 * 8]);
            gld16(&qkv[base + (size_t)(nt * 64 + row1) * 3072 + 1024 + h * 64 + oct1 * 8], &Kt[nb][c1 * 8]);
            gld16(&vTbh[(size_t)row0 * 2048 + nt * 64 + oct0 * 8], &Vt[nb][c0 * 8]);
            gld16(&vTbh[(size_t)row1 * 2048 + nt * 64 + oct1 * 8], &Vt[nb][c1 * 8]);
        }
        const U16* KtC = &Kt[kt & 1][0];
        const U16* VtC = &Vt[kt & 1][0];

        // ---- QK^T ----
        f32x4 s[4];
#pragma unroll
        for (int c = 0; c < 4; c++) {
            bf16x8 k0 = *(const bf16x8*)&KtC[(c * 16 + l15) * 64 + s0];
            bf16x8 k1 = *(const bf16x8*)&KtC[(c * 16 + l15) * 64 + (s0 ^ 32)];
            f32x4 z = (f32x4){0.f, 0.f, 0.f, 0.f};
            z = __builtin_amdgcn_mfma_f32_16x16x32_bf16(qf[0], k0, z, 0, 0, 0);
            z = __builtin_amdgcn_mfma_f32_16x16x32_bf16(qf[1], k1, z, 0, 0, 0);
            s[c] = z;
        }

        // ---- static softmax + swizzled P store ----
        U16* pb = &Pb[wave][0];
#pragma unroll
        for (int r = 0; r < 4; r++) {
            int q = quad * 4 + r;
#pragma unroll
            for (int c = 0; c < 4; c++) {
                float p = __builtin_amdgcn_exp2f(s[c][r] * sc2);
                l_i[r] += p;
                int key = c * 16 + l15;
                int idx = q * 64 + (((key >> 3) ^ (q & 7)) * 8) + (key & 7);
                union { float f; unsigned int u; } cv; cv.f = p;
                pb[idx] = (U16)(cv.u >> 16);
            }
        }

        // wave-local: drain our ds_writes before the cross-lane ds_read
        asm volatile("s_waitcnt lgkmcnt(0)" ::: "memory");

        bf16x8 pf0 = *(const bf16x8*)&pb[l15 * 64 + s0];
        bf16x8 pf1 = *(const bf16x8*)&pb[l15 * 64 + (s0 ^ 32)];
#pragma unroll
        for (int f = 0; f < 4; f++) {
            bf16x8 vf0 = *(const bf16x8*)&VtC[(f * 16 + l15) * 64 + s0];
            bf16x8 vf1 = *(const bf16x8*)&VtC[(f * 16 + l15) * 64 + (s0 ^ 32)];
            o[f] = __builtin_amdgcn_mfma_f32_16x16x32_bf16(pf0, vf0, o[f], 0, 0, 0);
            o[f] = __builtin_amdgcn_mfma_f32_16x16x32_bf16(pf1, vf1, o[f], 0, 0, 0);
        }
        __syncthreads();  // protects buf reuse AND makes prefetch visible
    }

#pragma unroll
    for (int r = 0; r < 4; r++) {
        float l = l_i[r];
#pragma unroll
        for (int off = 8; off >= 1; off >>= 1)
            l += __shfl_xor(l, off, 16);
        l_i[r] = 1.0f / l;
    }
#pragma unroll
    for (int f = 0; f < 4; f++) {
#pragma unroll
        for (int r = 0; r < 4; r++) {
            int row = b * 2048 + qt * 64 + wave * 16 + quad * 4 + r;
            int col = h * 64 + f * 16 + l15;
            attn_out[(size_t)row * 1024 + col] = f2b(o[f][r] * l_i[r]);
        }
    }
}

extern "C" void kernel_launch(void* const* d_in, const int* in_sizes, int n_in,
                              void* d_out, int out_size, void* d_ws, size_t ws_size,
                              hipStream_t stream) {
    (void)in_sizes; (void)n_in; (void)out_size; (void)ws_size;
    const float* x    = (const float*)d_in[0];
    const float* g    = (const float*)d_in[1];
    const float* be   = (const float*)d_in[2];
    const float* Wqkv = (const float*)d_in[3];
    const float* Wout = (const float*)d_in[4];
    const float* bout = (const float*)d_in[5];
    float* out = (float*)d_out;   // reference output dtype is fp32
    char* ws = (char*)d_ws;

    U16* xn   = (U16*)(ws);                          // 8 MB, reused as aout
    U16* qkv  = (U16*)(ws + (size_t)(8u  << 20));    // 24 MB (V third unused)
    U16* WqT  = (U16*)(ws + (size_t)(32u << 20));    // 6 MB
    U16* WoT  = (U16*)(ws + (size_t)(38u << 20));    // 2 MB
    U16* vT   = (U16*)(ws + (size_t)(40u << 20));    // 8 MB: V transposed
    U16* aout = xn;  // xn dead after GEMM1

    transpose_f2b<<<dim3(3072 / 32, 1024 / 32), dim3(32, 8), 0, stream>>>(Wqkv, WqT, 1024, 3072);
    transpose_f2b<<<dim3(1024 / 32, 1024 / 32), dim3(32, 8), 0, stream>>>(Wout, WoT, 1024, 1024);
    ln_kernel<<<4096, 256, 0, stream>>>(x, g, be, xn);
    gemm_bt<U16><<<dim3(3072 / 128, 4096 / 128), 256, 0, stream>>>(xn, WqT, nullptr, qkv, vT, 4096, 3072, 1024);
    attn_kernel<<<dim3(32, 32), 256, 0, stream>>>(qkv, vT, aout);
    gemm_bt<float><<<dim3(1024 / 128, 4096 / 128), 256, 0, stream>>>(aout, WoT, bout, out, nullptr, 4096, 1024, 1024);
}